// Round 10
// baseline (3982.642 us; speedup 1.0000x reference)
//
#include <hip/hip_runtime.h>
#include <stdint.h>

// LSTM: B=256, T=512, D=128, H=512, C=10
// R10 = R9 frame + R7 sentinel protocol + poll backoff.
// Persistent: 128 blocks x 4 waves. 16 groups x 8 blocks (g=bid&15); group
// owns 16 batches; each wave owns 16 hidden units (64 gate rows), K=640.
// W_ih/W_hh fragments in unified VGPR/AGPR file. h exchanged via a DEPTH-8
// ring of relaxed agent-scope 8B atomics primed with fp16-NaN sentinel
// 0x7E7E: the data is its own ready-flag. Serial chain per step is just
// h-store flight -> consumer validate -> h-MFMA -> gates (no drain, no flag).
// s_sleep(2) between failed polls tames the R7 poll-flood (314MB FETCH).
// X(t+1) raw-prefetched at loop top; xp(t+1) MFMA'd after publish (R9 trick).

#define T_STEPS 512
#define BATCH   256
#define DIM     128
#define HID     512
#define NGRP    16
#define BT      16
#define DEPTH   8

typedef _Float16 half8 __attribute__((ext_vector_type(8)));
typedef _Float16 half4 __attribute__((ext_vector_type(4)));
typedef float    f32x4 __attribute__((ext_vector_type(4)));

#define SLOT_HALFS (BATCH * HID)
#define WS_NEEDED  (DEPTH * SLOT_HALFS * 2)   // 2 MiB ring, memset to 0x7E

__device__ __forceinline__ half8 cvt8(f32x4 a, f32x4 b) {
  half8 r;
  r[0]=(_Float16)a[0]; r[1]=(_Float16)a[1]; r[2]=(_Float16)a[2]; r[3]=(_Float16)a[3];
  r[4]=(_Float16)b[0]; r[5]=(_Float16)b[1]; r[6]=(_Float16)b[2]; r[7]=(_Float16)b[3];
  return r;
}
__device__ __forceinline__ half8 load8_cvt(const float* p) {
  const f32x4* q = (const f32x4*)p;
  return cvt8(q[0], q[1]);
}
__device__ __forceinline__ float fsig(float x) {
  return __builtin_amdgcn_rcpf(1.f + __expf(-x));
}
__device__ __forceinline__ float ftanh(float x) {
  return 1.f - 2.f * __builtin_amdgcn_rcpf(1.f + __expf(2.f * x));
}

union h4u { unsigned long long u; half4 h; };
union h8u { unsigned long long u2[2]; half8 h; };

#define SENT8 0x7E7E7E7E7E7E7E7Eull           // 4x fp16 NaN (never a valid h)

__global__ __launch_bounds__(256, 1) void lstm_persistent(
    const float* __restrict__ X,   const float* __restrict__ Wih,
    const float* __restrict__ Whh, const float* __restrict__ bih,
    const float* __restrict__ bhh, const float* __restrict__ Wlin,
    float* __restrict__ out, _Float16* __restrict__ hbuf)
{
  const int tid  = threadIdx.x;
  const int w    = tid >> 6;
  const int lane = tid & 63;
  const int col  = lane & 15;        // batch-within-group (B/C col), W A-frag row
  const int q    = lane >> 4;        // 0..3
  const int bid  = blockIdx.x;
  const int g    = bid & 15;         // group
  const int blk  = bid >> 4;         // 0..7 within group
  const int J    = blk * 64 + w * 16;   // hidden-unit base owned by this wave
  const int b_my = g * BT + col;     // this lane's batch

  // ---- W fragments into registers (once) ----
  half8 whh[16][4];                  // [k-chunk of 32][gate]
  half8 wih[4][4];
  #pragma unroll
  for (int kc = 0; kc < 16; ++kc)
    #pragma unroll
    for (int mt = 0; mt < 4; ++mt) {
      const int row = mt * HID + J + col;
      whh[kc][mt] = load8_cvt(Whh + (size_t)row * HID + kc * 32 + q * 8);
    }
  #pragma unroll
  for (int xc = 0; xc < 4; ++xc)
    #pragma unroll
    for (int mt = 0; mt < 4; ++mt) {
      const int row = mt * HID + J + col;
      wih[xc][mt] = load8_cvt(Wih + (size_t)row * DIM + xc * 32 + q * 8);
    }

  float bias[4][4], c_st[4], hsum[4];
  #pragma unroll
  for (int mt = 0; mt < 4; ++mt)
    #pragma unroll
    for (int r = 0; r < 4; ++r) {
      const int row = mt * HID + J + q * 4 + r;
      bias[mt][r] = bih[row] + bhh[row];
    }
  #pragma unroll
  for (int r = 0; r < 4; ++r) { c_st[r] = 0.f; hsum[r] = 0.f; }

  const float* Xb = X + (size_t)b_my * T_STEPS * DIM;

  // ---- prologue: X(0) prefetch + acc = xp(0) ----
  f32x4 xraw[8];
  #pragma unroll
  for (int xc = 0; xc < 4; ++xc) {
    const f32x4* p = (const f32x4*)(Xb + xc * 32 + q * 8);
    xraw[2 * xc] = p[0]; xraw[2 * xc + 1] = p[1];
  }
  f32x4 acc[4];
  #pragma unroll
  for (int mt = 0; mt < 4; ++mt) acc[mt] = (f32x4){0.f, 0.f, 0.f, 0.f};
  #pragma unroll
  for (int xc = 0; xc < 4; ++xc) {
    half8 xb = cvt8(xraw[2 * xc], xraw[2 * xc + 1]);
    #pragma unroll
    for (int mt = 0; mt < 4; ++mt)
      acc[mt] = __builtin_amdgcn_mfma_f32_16x16x32_f16(wih[xc][mt], xb, acc[mt], 0, 0, 0);
  }

  for (int t = 0; t < T_STEPS; ++t) {
    // issue X(t+1) raw prefetch (clamped; drained before xp(t+1) use)
    {
      const int tn = (t + 1 < T_STEPS) ? (t + 1) : (T_STEPS - 1);
      const float* xp = Xb + (size_t)tn * DIM + q * 8;
      #pragma unroll
      for (int xc = 0; xc < 4; ++xc) {
        const f32x4* src = (const f32x4*)(xp + xc * 32);
        xraw[2 * xc]     = src[0];
        xraw[2 * xc + 1] = src[1];
      }
    }

    // consume h(t): poll the data itself (sentinel = not yet written),
    // s_sleep backoff between failed attempts (tames MALL poll flood)
    if (t > 0) {
      const unsigned long long* hp =
          (const unsigned long long*)(hbuf + (size_t)(t & (DEPTH - 1)) * SLOT_HALFS
                                      + (size_t)b_my * HID) + q * 2;
      unsigned long long lo[16], hi[16];
      for (;;) {
        #pragma unroll
        for (int kc = 0; kc < 16; ++kc) {
          lo[kc] = __hip_atomic_load(hp + kc * 8,     __ATOMIC_RELAXED, __HIP_MEMORY_SCOPE_AGENT);
          hi[kc] = __hip_atomic_load(hp + kc * 8 + 1, __ATOMIC_RELAXED, __HIP_MEMORY_SCOPE_AGENT);
        }
        unsigned bad = 0;
        #pragma unroll
        for (int kc = 0; kc < 16; ++kc) {
          bad |= (((unsigned)lo[kc] & 0xFFFFu) == 0x7E7Eu);
          bad |= (((unsigned)hi[kc] & 0xFFFFu) == 0x7E7Eu);
        }
        if (__all((int)(bad == 0))) break;
        __builtin_amdgcn_s_sleep(2);   // ~128 cyc backoff
      }
      __builtin_amdgcn_sched_barrier(0);  // nothing crosses the validation

      #pragma unroll
      for (int kc = 0; kc < 16; ++kc) {
        h8u u; u.u2[0] = lo[kc]; u.u2[1] = hi[kc];
        #pragma unroll
        for (int mt = 0; mt < 4; ++mt)
          acc[mt] = __builtin_amdgcn_mfma_f32_16x16x32_f16(whh[kc][mt], u.h, acc[mt], 0, 0, 0);
      }
    }

    // gates -> c,h ; each lane owns units J+q*4..+3 for batch col
    h4u hv;
    #pragma unroll
    for (int r = 0; r < 4; ++r) {
      const float ig = fsig(acc[0][r] + bias[0][r]);
      const float fg = fsig(acc[1][r] + bias[1][r]);
      const float gg = ftanh(acc[2][r] + bias[2][r]);
      const float og = fsig(acc[3][r] + bias[3][r]);
      const float cc = fg * c_st[r] + ig * gg;
      c_st[r] = cc;
      const float h = og * ftanh(cc);
      hsum[r] += h;
      hv.h[r] = (_Float16)h;
    }

    // publish h(t+1): ONE 8B atomic store — the data is the signal
    const size_t my_off = (size_t)b_my * HID + J + q * 4;
    unsigned long long* hw =
        (unsigned long long*)(hbuf + (size_t)((t + 1) & (DEPTH - 1)) * SLOT_HALFS + my_off);
    __hip_atomic_store(hw, hv.u, __ATOMIC_RELAXED, __HIP_MEMORY_SCOPE_AGENT);

    // re-prime the slot consumed at iter t-2 (next reused at iter t+6);
    // 5 iterations of natural waitcnt drains before reuse (R7-proven safe)
    unsigned long long* pr =
        (unsigned long long*)(hbuf + (size_t)((t + 6) & (DEPTH - 1)) * SLOT_HALFS + my_off);
    __hip_atomic_store(pr, SENT8, __ATOMIC_RELAXED, __HIP_MEMORY_SCOPE_AGENT);

    // xp(t+1) NOW — overlaps the h-store flight (off the serial path)
    if (t + 1 < T_STEPS) {
      #pragma unroll
      for (int mt = 0; mt < 4; ++mt) acc[mt] = (f32x4){0.f, 0.f, 0.f, 0.f};
      #pragma unroll
      for (int xc = 0; xc < 4; ++xc) {
        half8 xb = cvt8(xraw[2 * xc], xraw[2 * xc + 1]);
        #pragma unroll
        for (int mt = 0; mt < 4; ++mt)
          acc[mt] = __builtin_amdgcn_mfma_f32_16x16x32_f16(wih[xc][mt], xb, acc[mt], 0, 0, 0);
      }
    }
  }

  // epilogue: logits += mean_h * W_lin^T (bias pre-set by init kernel)
  const float inv = 1.0f / (float)T_STEPS;
  float m[4];
  #pragma unroll
  for (int r = 0; r < 4; ++r) m[r] = hsum[r] * inv;
  #pragma unroll
  for (int cls = 0; cls < 10; ++cls) {
    f32x4 wl = *(const f32x4*)(Wlin + (size_t)cls * HID + J + q * 4);
    float p = m[0] * wl[0] + m[1] * wl[1] + m[2] * wl[2] + m[3] * wl[3];
    p += __shfl_xor(p, 16, 64);
    p += __shfl_xor(p, 32, 64);
    if (q == 0) atomicAdd(out + b_my * 10 + cls, p);
  }
}

__global__ void init_out(const float* __restrict__ blin, float* __restrict__ out) {
  const int i = blockIdx.x * blockDim.x + threadIdx.x;
  if (i < BATCH * 10) out[i] = blin[i % 10];
}

extern "C" void kernel_launch(void* const* d_in, const int* in_sizes, int n_in,
                              void* d_out, int out_size, void* d_ws, size_t ws_size,
                              hipStream_t stream) {
  const float* X    = (const float*)d_in[0];
  const float* Wih  = (const float*)d_in[1];
  const float* Whh  = (const float*)d_in[2];
  const float* bih  = (const float*)d_in[3];
  const float* bhh  = (const float*)d_in[4];
  const float* Wlin = (const float*)d_in[5];
  const float* blin = (const float*)d_in[6];
  float* out = (float*)d_out;

  if (ws_size < (size_t)WS_NEEDED) return;

  _Float16* hbuf = (_Float16*)d_ws;

  hipMemsetAsync(d_ws, 0x7E, WS_NEEDED, stream);  // prime whole ring with sentinel
  init_out<<<10, 256, 0, stream>>>(blin, out);
  lstm_persistent<<<128, 256, 0, stream>>>(X, Wih, Whh, bih, bhh, Wlin, out, hbuf);
}